// Round 6
// baseline (194.252 us; speedup 1.0000x reference)
//
#include <hip/hip_runtime.h>

#define CCH 16
#define DD 64
#define HH 96
#define WW 96
#define HW (HH*WW)
#define DHW (DD*HH*WW)   // 589824
#define CH4 (DHW/4)      // 147456
#define NTH 384
#define KTR 1.08f        // 27 * k_harris (S kept unscaled by 1/27; ranking-invariant)

// DPP row16 shifts: thread layout is lh-fast (lh = tid & 15), so a DPP row of
// 16 lanes == one h-column; bound_ctrl=true zero-fills at row ends (the filled
// sites only feed non-emitted outputs). Harris is invariant to an up/down swap
// (all terms have even degree in each gradient; a swap only flips gy's sign).
__device__ __forceinline__ float dpp_up(float v) {
    return __int_as_float(__builtin_amdgcn_update_dpp(
        0, __float_as_int(v), 0x111 /*row_shr:1*/, 0xF, 0xF, true));
}
__device__ __forceinline__ float dpp_dn(float v) {
    return __int_as_float(__builtin_amdgcn_update_dpp(
        0, __float_as_int(v), 0x101 /*row_shl:1*/, 0xF, 0xF, true));
}

// Load 8 x values at w = wb-2 .. wb+5 for slice e (zero at OOB row/slice/edge).
__device__ __forceinline__ void load8(float v[8], const float* __restrict__ xc,
                                      int e, int roff, bool rowok, bool lok, bool rok) {
    if (rowok && (unsigned)e < DD) {
        const float* s = xc + (size_t)e * HW + roff;
        const float4 m = *(const float4*)s;            // 16B aligned
        v[2] = m.x; v[3] = m.y; v[4] = m.z; v[5] = m.w;
        if (lok) { const float2 l = *(const float2*)(s - 2); v[0] = l.x; v[1] = l.y; }
        else     { v[0] = v[1] = 0.f; }
        if (rok) { const float2 r = *(const float2*)(s + 4); v[6] = r.x; v[7] = r.y; }
        else     { v[6] = v[7] = 0.f; }
    } else {
        #pragma unroll
        for (int j = 0; j < 8; ++j) v[j] = 0.f;
    }
}

// Depth-sweep separable Harris, zero LDS / zero barriers in the main loop.
// Thread owns 4 w sites + computes products redundantly at 1 halo site each
// side (w-convs register-internal); h-convs via DPP row shifts (VALU pipe).
// Block: 384 threads = 16 lh x 24 lc; grid (8 h-tiles, 4 d-chunks, 16 ch).
// Per-block partial written to its own slot -> no ws zero-init, no atomics.
__global__ __launch_bounds__(NTH, 3)
void harris_sum_kernel(const float* __restrict__ x, float* __restrict__ pp) {
    __shared__ float red[6];

    const int tid = threadIdx.x;
    const int lh = tid & 15, lc = tid >> 4;          // lc 0..23
    const int c  = blockIdx.z;
    const int H0 = blockIdx.x * 12;
    const int o0 = blockIdx.y * 16;
    const int gh = H0 + lh - 2;
    const bool rowok = ((unsigned)gh < HH);
    const float mask = rowok ? 1.f : 0.f;            // box zero-pads products at OOB rows
    const bool lok = (lc > 0), rok = (lc < 23);
    const float lmask = lok ? 1.f : 0.f;             // products at w=-1 / w=96 are zero
    const float rmask = rok ? 1.f : 0.f;
    const float* xc = x + (size_t)c * DHW;
    const int roff = gh * WW + (lc << 2);

    float xp[8], xm[8], xn[8];
    load8(xp, xc, o0 - 2, roff, rowok, lok, rok);
    load8(xm, xc, o0 - 1, roff, rowok, lok, rok);
    load8(xn, xc, o0,     roff, rowok, lok, rok);

    float s2m1[6][4], s2m2[6][4];
    #pragma unroll
    for (int f = 0; f < 6; ++f)
        #pragma unroll
        for (int i = 0; i < 4; ++i) { s2m1[f][i] = 0.f; s2m2[f][i] = 0.f; }
    float hs = 0.f;
    const bool emit_row = (lh >= 2) && (lh <= 13);

    for (int e = o0 - 1; e <= o0 + 16; ++e) {
        float xf[8];
        load8(xf, xc, e + 2, roff, rowok, lok, rok);   // prefetch

        float R[6][4];
        if ((unsigned)e < DD) {                        // block-uniform branch
            float A[8], Dz[8];
            #pragma unroll
            for (int j = 0; j < 8; ++j) {
                A[j]  = xp[j] + xm[j] + xn[j];         // depth [1,1,1]
                Dz[j] = xn[j] - xp[j];                 // depth [-1,0,1]
            }
            #pragma unroll
            for (int f = 0; f < 6; ++f)
                #pragma unroll
                for (int i = 0; i < 4; ++i) R[f][i] = 0.f;

            #pragma unroll
            for (int k = 0; k < 6; ++k) {              // site w = wb-1+k, A index j=k+1
                const int j = k + 1;
                float Sx = A[j+1] - A[j-1];            // w [-1,0,1] on A
                float Tx = A[j-1] + 2.f*A[j] + A[j+1]; // w [1,2,1]  on A
                float Td = Dz[j-1] + Dz[j] + Dz[j+1];  // w [1,1,1]  on Dz
                float m = mask;
                if (k == 0) m *= lmask;
                if (k == 5) m *= rmask;
                float gx = (dpp_up(Sx) + 2.f*Sx + dpp_dn(Sx)) * m;  // h [1,2,1]
                float gy = (dpp_dn(Tx) - dpp_up(Tx)) * m;           // h [-1,0,1]
                float gz = (dpp_up(Td) + Td + dpp_dn(Td)) * m;      // h [1,1,1]
                float P0 = gx*gx, P1 = gy*gy, P2 = gz*gz;
                float P3 = gx*gy, P4 = gx*gz, P5 = gy*gz;
                // scatter-accumulate into product w-conv: R[i] += P[k], i in {k-2..k} n [0,3]
                #pragma unroll
                for (int i = 0; i < 4; ++i) {
                    if (k >= i && k <= i + 2) {
                        R[0][i] += P0; R[1][i] += P1; R[2][i] += P2;
                        R[3][i] += P3; R[4][i] += P4; R[5][i] += P5;
                    }
                }
            }
        } else {
            #pragma unroll
            for (int f = 0; f < 6; ++f)
                #pragma unroll
                for (int i = 0; i < 4; ++i) R[f][i] = 0.f;
        }

        const bool emit = (e > o0) && emit_row;
        #pragma unroll
        for (int i = 0; i < 4; ++i) {
            // s2c = h [1,1,1] on R (DPP), fused with emit + history shift
            float t0 = dpp_up(R[0][i]) + R[0][i] + dpp_dn(R[0][i]);
            float t1 = dpp_up(R[1][i]) + R[1][i] + dpp_dn(R[1][i]);
            float t2 = dpp_up(R[2][i]) + R[2][i] + dpp_dn(R[2][i]);
            float t3 = dpp_up(R[3][i]) + R[3][i] + dpp_dn(R[3][i]);
            float t4 = dpp_up(R[4][i]) + R[4][i] + dpp_dn(R[4][i]);
            float t5 = dpp_up(R[5][i]) + R[5][i] + dpp_dn(R[5][i]);
            if (emit) {     // output slice o = e-1: depth [1,1,1] over S2 history
                float sxx = s2m2[0][i] + s2m1[0][i] + t0;
                float syy = s2m2[1][i] + s2m1[1][i] + t1;
                float szz = s2m2[2][i] + s2m1[2][i] + t2;
                float sxy = s2m2[3][i] + s2m1[3][i] + t3;
                float sxz = s2m2[4][i] + s2m1[4][i] + t4;
                float syz = s2m2[5][i] + s2m1[5][i] + t5;
                float det = sxx*(syy*szz - syz*syz)
                          - sxy*(sxy*szz - syz*sxz)
                          + sxz*(sxy*syz - syy*sxz);
                float tr = sxx + syy + szz;
                hs += det - KTR * tr * tr;   // unscaled by 27^-3: ranking-invariant
            }
            s2m2[0][i] = s2m1[0][i]; s2m1[0][i] = t0;
            s2m2[1][i] = s2m1[1][i]; s2m1[1][i] = t1;
            s2m2[2][i] = s2m1[2][i]; s2m1[2][i] = t2;
            s2m2[3][i] = s2m1[3][i]; s2m1[3][i] = t3;
            s2m2[4][i] = s2m1[4][i]; s2m1[4][i] = t4;
            s2m2[5][i] = s2m1[5][i]; s2m1[5][i] = t5;
        }
        #pragma unroll
        for (int j = 0; j < 8; ++j) { xp[j] = xm[j]; xm[j] = xn[j]; xn[j] = xf[j]; }
    }

    // block reduce -> per-block partial slot (no atomics, no init needed)
    #pragma unroll
    for (int o = 32; o > 0; o >>= 1) hs += __shfl_down(hs, o, 64);
    if ((tid & 63) == 0) red[tid >> 6] = hs;
    __syncthreads();
    if (tid == 0)
        pp[c * 32 + blockIdx.y * 8 + blockIdx.x] =
            red[0] + red[1] + red[2] + red[3] + red[4] + red[5];
}

// Sum 32 partials/channel, top-8 select (strict >: stable ties), gather copy.
__global__ __launch_bounds__(256)
void gather_topk_kernel(const float* __restrict__ x, const float* __restrict__ pp,
                        float4* __restrict__ out) {
    __shared__ float pv[CCH];
    __shared__ int sidx[8];
    const int tid = threadIdx.x;
    if (tid < CCH) {
        float s = 0.f;
        #pragma unroll
        for (int j = 0; j < 32; ++j) s += pp[tid * 32 + j];
        pv[tid] = s;   // fixed order -> deterministic; common scale irrelevant to ranking
    }
    __syncthreads();
    if (tid == 0) {
        bool used[CCH];
        #pragma unroll
        for (int i = 0; i < CCH; ++i) used[i] = false;
        for (int j = 0; j < 8; ++j) {
            int best = 0; float bv = -__builtin_inff();
            for (int i = 0; i < CCH; ++i)
                if (!used[i] && pv[i] > bv) { bv = pv[i]; best = i; }
            used[best] = true;
            sidx[j] = best;
        }
    }
    __syncthreads();
    const int j   = blockIdx.y;                      // 0..7
    const int pos = blockIdx.x * 256 + tid;          // 576*256 == CH4 exact
    const int cidx = sidx[j];
    const float4* src = (const float4*)(x + (size_t)cidx * DHW);
    out[(size_t)j * CH4 + pos] = src[pos];
}

extern "C" void kernel_launch(void* const* d_in, const int* in_sizes, int n_in,
                              void* d_out, int out_size, void* d_ws, size_t ws_size,
                              hipStream_t stream) {
    const float* x = (const float*)d_in[0];
    float4* out = reinterpret_cast<float4*>(d_out);
    float* pp = (float*)d_ws;                        // 512 per-block partials (2 KB)

    dim3 g1(8, 4, CCH);                              // 512 blocks, 2/CU
    harris_sum_kernel<<<g1, NTH, 0, stream>>>(x, pp);

    dim3 g2(CH4 / 256, 8, 1);                        // (576, 8)
    gather_topk_kernel<<<g2, 256, 0, stream>>>(x, pp, out);
}

// Round 7
// 191.381 us; speedup vs baseline: 1.0150x; 1.0150x over previous
//
#include <hip/hip_runtime.h>

#define CCH 16
#define DD 64
#define HH 96
#define WW 96
#define HW (HH*WW)
#define DHW (DD*HH*WW)   // 589824
#define CH4 (DHW/4)      // 147456
#define NTH 384
#define DCH 8            // depth chunk (outputs per block)
#define NBY (DD/DCH)     // 8 depth chunks
#define KTR 1.08f        // 27 * k_harris (S unscaled by 1/27; ranking-invariant)

// DPP row16 shifts: thread layout is lh-fast (lh = tid & 15), so a DPP row of
// 16 lanes == one h-column; bound_ctrl=true zero-fills at row ends (filled
// sites only feed non-emitted outputs). Harris is invariant to an up/down swap
// (every term has even degree in each gradient; a swap only flips gy's sign).
__device__ __forceinline__ float dpp_up(float v) {
    return __int_as_float(__builtin_amdgcn_update_dpp(
        0, __float_as_int(v), 0x111 /*row_shr:1*/, 0xF, 0xF, true));
}
__device__ __forceinline__ float dpp_dn(float v) {
    return __int_as_float(__builtin_amdgcn_update_dpp(
        0, __float_as_int(v), 0x101 /*row_shl:1*/, 0xF, 0xF, true));
}

__device__ __forceinline__ void load4(float v[4], const float* __restrict__ xc,
                                      int e, int woff, bool rowok) {
    if (rowok && (unsigned)e < DD) {
        const float4 t = *(const float4*)(xc + (size_t)e * HW + woff);
        v[0] = t.x; v[1] = t.y; v[2] = t.z; v[3] = t.w;
    } else {
        v[0] = v[1] = v[2] = v[3] = 0.f;
    }
}

// Depth-sweep separable Harris; thread owns 4 consecutive w sites (float4);
// w-convs register-internal + LDS edge exchange; h-convs via DPP (VALU pipe).
// Block: 384 threads = 16 lh x 24 lc covers full W=96, h-tile 12 (+2 halo).
// Grid (8 h-tiles, 8 d-chunks, 16 ch) = 1024 blocks -> 4 blocks/CU, 24 waves/CU.
__global__ __launch_bounds__(NTH, 3)
void harris_sum_kernel(const float* __restrict__ x, float* __restrict__ pp) {
    __shared__ float eA[4][NTH];    // A.x, A.w, Dz.x, Dz.w edges
    __shared__ float eP[12][NTH];   // P[f].x, P[f].w edges
    __shared__ float red[6];

    const int tid = threadIdx.x;
    const int lh = tid & 15, lc = tid >> 4;
    const int c  = blockIdx.z;
    const int H0 = blockIdx.x * 12;
    const int o0 = blockIdx.y * DCH;
    const int gh = H0 + lh - 2;
    const bool rowok = ((unsigned)gh < HH);
    const float mask = rowok ? 1.f : 0.f;   // zero products at OOB rows (box zero-pad)
    const float* xc = x + (size_t)c * DHW;
    const int woff = gh * WW + (lc << 2);

    // rolling x window: xp=x(e-1), xm=x(e), xn=x(e+1)
    float xp[4], xm[4], xn[4];
    load4(xp, xc, o0 - 2, woff, rowok);
    load4(xm, xc, o0 - 1, woff, rowok);
    load4(xn, xc, o0,     woff, rowok);

    float s2m1[6][4], s2m2[6][4];
    #pragma unroll
    for (int f = 0; f < 6; ++f)
        #pragma unroll
        for (int i = 0; i < 4; ++i) { s2m1[f][i] = 0.f; s2m2[f][i] = 0.f; }
    float hs = 0.f;
    const bool emit_row = (lh >= 2) && (lh <= 13);

    for (int e = o0 - 1; e <= o0 + DCH; ++e) {   // 10 slices -> 8 output slices
        float xf[4];
        load4(xf, xc, e + 2, woff, rowok);       // prefetch next slice

        float s2c[6][4];
        if ((unsigned)e < DD) {                  // block-uniform branch
            float A[4], Dz[4];
            #pragma unroll
            for (int i = 0; i < 4; ++i) {
                A[i]  = xp[i] + xm[i] + xn[i];   // depth [1,1,1]
                Dz[i] = xn[i] - xp[i];           // depth [-1,0,1]
            }
            eA[0][tid] = A[0];  eA[1][tid] = A[3];
            eA[2][tid] = Dz[0]; eA[3][tid] = Dz[3];
            __syncthreads();
            float Alw = (lc > 0)  ? eA[1][tid - 16] : 0.f;
            float Dlw = (lc > 0)  ? eA[3][tid - 16] : 0.f;
            float Arx = (lc < 23) ? eA[0][tid + 16] : 0.f;
            float Drx = (lc < 23) ? eA[2][tid + 16] : 0.f;
            const float Al[4] = {Alw, A[0], A[1], A[2]};
            const float Ar[4] = {A[1], A[2], A[3], Arx};
            const float Dl[4] = {Dlw, Dz[0], Dz[1], Dz[2]};
            const float Dr[4] = {Dz[1], Dz[2], Dz[3], Drx};

            float P[6][4];
            #pragma unroll
            for (int i = 0; i < 4; ++i) {
                float Sx = Ar[i] - Al[i];               // w [-1,0,1] on A
                float Tx = Al[i] + 2.f*A[i] + Ar[i];    // w [1,2,1]  on A
                float Td = Dl[i] + Dz[i] + Dr[i];       // w [1,1,1]  on Dz
                float gx = (dpp_up(Sx) + 2.f*Sx + dpp_dn(Sx)) * mask;  // h [1,2,1]
                float gy = (dpp_dn(Tx) - dpp_up(Tx)) * mask;           // h [-1,0,1]
                float gz = (dpp_up(Td) + Td + dpp_dn(Td)) * mask;      // h [1,1,1]
                P[0][i] = gx*gx; P[1][i] = gy*gy; P[2][i] = gz*gz;
                P[3][i] = gx*gy; P[4][i] = gx*gz; P[5][i] = gy*gz;
            }
            #pragma unroll
            for (int f = 0; f < 6; ++f) { eP[2*f][tid] = P[f][0]; eP[2*f+1][tid] = P[f][3]; }
            __syncthreads();
            #pragma unroll
            for (int f = 0; f < 6; ++f) {
                float pl = (lc > 0)  ? eP[2*f+1][tid - 16] : 0.f;
                float pr = (lc < 23) ? eP[2*f][tid + 16]   : 0.f;
                float R0 = pl      + P[f][0] + P[f][1];
                float R1 = P[f][0] + P[f][1] + P[f][2];
                float R2 = P[f][1] + P[f][2] + P[f][3];
                float R3 = P[f][2] + P[f][3] + pr;
                s2c[f][0] = dpp_up(R0) + R0 + dpp_dn(R0);   // h [1,1,1]
                s2c[f][1] = dpp_up(R1) + R1 + dpp_dn(R1);
                s2c[f][2] = dpp_up(R2) + R2 + dpp_dn(R2);
                s2c[f][3] = dpp_up(R3) + R3 + dpp_dn(R3);
            }
        } else {
            #pragma unroll
            for (int f = 0; f < 6; ++f)
                #pragma unroll
                for (int i = 0; i < 4; ++i) s2c[f][i] = 0.f;
        }

        if (e > o0 && emit_row) {   // emit output slice o = e-1
            #pragma unroll
            for (int i = 0; i < 4; ++i) {
                float sxx = s2m2[0][i] + s2m1[0][i] + s2c[0][i];
                float syy = s2m2[1][i] + s2m1[1][i] + s2c[1][i];
                float szz = s2m2[2][i] + s2m1[2][i] + s2c[2][i];
                float sxy = s2m2[3][i] + s2m1[3][i] + s2c[3][i];
                float sxz = s2m2[4][i] + s2m1[4][i] + s2c[4][i];
                float syz = s2m2[5][i] + s2m1[5][i] + s2c[5][i];
                float det = sxx*(syy*szz - syz*syz)
                          - sxy*(sxy*szz - syz*sxz)
                          + sxz*(sxy*syz - syy*sxz);
                float tr = sxx + syy + szz;
                hs += det - KTR * tr * tr;   // unscaled by 27^-3: ranking-invariant
            }
        }
        #pragma unroll
        for (int f = 0; f < 6; ++f)
            #pragma unroll
            for (int i = 0; i < 4; ++i) { s2m2[f][i] = s2m1[f][i]; s2m1[f][i] = s2c[f][i]; }
        #pragma unroll
        for (int i = 0; i < 4; ++i) { xp[i] = xm[i]; xm[i] = xn[i]; xn[i] = xf[i]; }
    }

    // block reduce -> per-block partial slot (no atomics, no ws init needed)
    #pragma unroll
    for (int o = 32; o > 0; o >>= 1) hs += __shfl_down(hs, o, 64);
    if ((tid & 63) == 0) red[tid >> 6] = hs;
    __syncthreads();
    if (tid == 0)
        pp[c * (NBY * 8) + blockIdx.y * 8 + blockIdx.x] =
            red[0] + red[1] + red[2] + red[3] + red[4] + red[5];
}

// Sum 64 partials/channel, top-8 select (strict >: stable ties), gather copy.
__global__ __launch_bounds__(256)
void gather_topk_kernel(const float* __restrict__ x, const float* __restrict__ pp,
                        float4* __restrict__ out) {
    __shared__ float pv[CCH];
    __shared__ int sidx[8];
    const int tid = threadIdx.x;
    if (tid < CCH) {
        float s = 0.f;
        #pragma unroll
        for (int j = 0; j < NBY * 8; ++j) s += pp[tid * (NBY * 8) + j];
        pv[tid] = s;   // fixed order -> deterministic across blocks
    }
    __syncthreads();
    if (tid == 0) {
        bool used[CCH];
        #pragma unroll
        for (int i = 0; i < CCH; ++i) used[i] = false;
        for (int j = 0; j < 8; ++j) {
            int best = 0; float bv = -__builtin_inff();
            for (int i = 0; i < CCH; ++i)
                if (!used[i] && pv[i] > bv) { bv = pv[i]; best = i; }
            used[best] = true;
            sidx[j] = best;
        }
    }
    __syncthreads();
    const int j   = blockIdx.y;                      // 0..7
    const int pos = blockIdx.x * 256 + tid;          // 576*256 == CH4 exact
    const int cidx = sidx[j];
    const float4* src = (const float4*)(x + (size_t)cidx * DHW);
    out[(size_t)j * CH4 + pos] = src[pos];
}

extern "C" void kernel_launch(void* const* d_in, const int* in_sizes, int n_in,
                              void* d_out, int out_size, void* d_ws, size_t ws_size,
                              hipStream_t stream) {
    const float* x = (const float*)d_in[0];
    float4* out = reinterpret_cast<float4*>(d_out);
    float* pp = (float*)d_ws;                        // 1024 per-block partials (4 KB)

    dim3 g1(8, NBY, CCH);                            // 1024 blocks -> 4/CU
    harris_sum_kernel<<<g1, NTH, 0, stream>>>(x, pp);

    dim3 g2(CH4 / 256, 8, 1);                        // (576, 8)
    gather_topk_kernel<<<g2, 256, 0, stream>>>(x, pp, out);
}